// Round 1
// baseline (421.929 us; speedup 1.0000x reference)
//
#include <hip/hip_runtime.h>
#include <math.h>

#define NN 50000
#define EE 400000
#define HD 256
#define NH 4
#define DH 64
#define NEG_SLOPE 0.2f

// ============================ CSR build ============================
__global__ void k_zero_i32(int* __restrict__ p, int n) {
  int i = blockIdx.x * blockDim.x + threadIdx.x;
  if (i < n) p[i] = 0;
}

__global__ void k_count(const int* __restrict__ dst, int* __restrict__ counts,
                        int* __restrict__ rank) {
  int e = blockIdx.x * blockDim.x + threadIdx.x;
  if (e < EE) rank[e] = atomicAdd(&counts[dst[e]], 1);
}

__global__ void k_scan1(const int* __restrict__ counts, int* __restrict__ row_ptr,
                        int* __restrict__ bsums) {
  __shared__ int sm[256];
  int i = blockIdx.x * 256 + threadIdx.x;
  int v = (i < NN) ? counts[i] : 0;
  sm[threadIdx.x] = v;
  __syncthreads();
  for (int off = 1; off < 256; off <<= 1) {
    int t = (threadIdx.x >= off) ? sm[threadIdx.x - off] : 0;
    __syncthreads();
    sm[threadIdx.x] += t;
    __syncthreads();
  }
  if (i < NN) row_ptr[i + 1] = sm[threadIdx.x];
  if (threadIdx.x == 255) bsums[blockIdx.x] = sm[255];
}

__global__ void k_scan2(int* __restrict__ bsums, int nb) {
  __shared__ int sm[256];
  int v = (threadIdx.x < nb) ? bsums[threadIdx.x] : 0;
  sm[threadIdx.x] = v;
  __syncthreads();
  for (int off = 1; off < 256; off <<= 1) {
    int t = (threadIdx.x >= off) ? sm[threadIdx.x - off] : 0;
    __syncthreads();
    sm[threadIdx.x] += t;
    __syncthreads();
  }
  if (threadIdx.x < nb) bsums[threadIdx.x] = sm[threadIdx.x] - v;  // exclusive
}

__global__ void k_scan3(int* __restrict__ row_ptr, const int* __restrict__ bsums) {
  int i = blockIdx.x * 256 + threadIdx.x;
  if (i < NN) row_ptr[i + 1] += bsums[blockIdx.x];
  if (blockIdx.x == 0 && threadIdx.x == 0) row_ptr[0] = 0;
}

__global__ void k_scatter(const int* __restrict__ src, const int* __restrict__ dst,
                          const int* __restrict__ row_ptr, const int* __restrict__ rank,
                          int* __restrict__ csr_src) {
  int e = blockIdx.x * blockDim.x + threadIdx.x;
  if (e < EE) csr_src[row_ptr[dst[e]] + rank[e]] = src[e];
}

// ============================ GEMM (fp32) ============================
// C[M,256] = A[idx[m], 256] @ W[256,256]; idx==nullptr -> identity
#define BM 128
#define BN 128
#define BK 16
#define PAD 4

__global__ __launch_bounds__(256) void k_gemm(const float* __restrict__ A,
                                              const int* __restrict__ idx,
                                              const float* __restrict__ W,
                                              float* __restrict__ C, int Mrows) {
  __shared__ float As[BK][BM + PAD];
  __shared__ float Bs[BK][BN + PAD];
  int tid = threadIdx.x;
  int row0 = blockIdx.x * BM;
  int col0 = blockIdx.y * BN;
  int tr = tid / 16, tc = tid % 16;  // 16x16 thread grid, 8x8 micro-tile
  float acc[8][8];
#pragma unroll
  for (int i = 0; i < 8; ++i)
#pragma unroll
    for (int j = 0; j < 8; ++j) acc[i][j] = 0.f;

  for (int k0 = 0; k0 < HD; k0 += BK) {
    // A tile: 128 rows x 16 cols = 512 float4; 2 per thread (transposed store)
#pragma unroll
    for (int i = 0; i < 2; ++i) {
      int t = tid + i * 256;
      int r = t >> 2;            // 0..127
      int kk = (t & 3) * 4;      // 0,4,8,12
      int gr = row0 + r;
      float4 v = make_float4(0.f, 0.f, 0.f, 0.f);
      if (gr < Mrows) {
        int ar = idx ? idx[gr] : gr;
        v = *(const float4*)&A[(size_t)ar * HD + k0 + kk];
      }
      As[kk + 0][r] = v.x;
      As[kk + 1][r] = v.y;
      As[kk + 2][r] = v.z;
      As[kk + 3][r] = v.w;
    }
    // B tile: 16 rows x 128 cols = 512 float4; 2 per thread
#pragma unroll
    for (int i = 0; i < 2; ++i) {
      int t = tid + i * 256;
      int r = t >> 5;            // 0..15
      int c = (t & 31) * 4;      // 0..124
      *(float4*)&Bs[r][c] = *(const float4*)&W[(size_t)(k0 + r) * HD + col0 + c];
    }
    __syncthreads();
#pragma unroll
    for (int k = 0; k < BK; ++k) {
      float a[8], b[8];
      *(float4*)&a[0] = *(float4*)&As[k][tr * 8];
      *(float4*)&a[4] = *(float4*)&As[k][tr * 8 + 4];
      *(float4*)&b[0] = *(float4*)&Bs[k][tc * 8];
      *(float4*)&b[4] = *(float4*)&Bs[k][tc * 8 + 4];
#pragma unroll
      for (int i = 0; i < 8; ++i)
#pragma unroll
        for (int j = 0; j < 8; ++j) acc[i][j] = fmaf(a[i], b[j], acc[i][j]);
    }
    __syncthreads();
  }
#pragma unroll
  for (int i = 0; i < 8; ++i) {
    int gr = row0 + tr * 8 + i;
    if (gr < Mrows) {
#pragma unroll
      for (int j = 0; j < 8; j += 4)
        *(float4*)&C[(size_t)gr * HD + col0 + tc * 8 + j] = *(float4*)&acc[i][j];
    }
  }
}

// ============================ attn logits ============================
// el[n,h] = sum_d f[n,h,d]*al[h,d]; er likewise. One wave per node.
__global__ __launch_bounds__(256) void k_logits(const float* __restrict__ f,
                                                const float* __restrict__ al,
                                                const float* __restrict__ ar,
                                                float* __restrict__ el,
                                                float* __restrict__ er) {
  int node = blockIdx.x * 4 + (threadIdx.x >> 6);
  if (node >= NN) return;
  int lane = threadIdx.x & 63;
  int head = lane >> 4;
  float4 fv = ((const float4*)(f + (size_t)node * HD))[lane];
  const float4 av = ((const float4*)al)[lane];
  const float4 rv = ((const float4*)ar)[lane];
  float sl = fv.x * av.x + fv.y * av.y + fv.z * av.z + fv.w * av.w;
  float sr = fv.x * rv.x + fv.y * rv.y + fv.z * rv.z + fv.w * rv.w;
#pragma unroll
  for (int off = 1; off < 16; off <<= 1) {
    sl += __shfl_xor(sl, off);
    sr += __shfl_xor(sr, off);
  }
  if ((lane & 15) == 0) {
    el[node * NH + head] = sl;
    er[node * NH + head] = sr;
  }
}

// ============================ aggregation ============================
// One wave per dst node: segment softmax (2 passes) + weighted gather-sum.
__global__ __launch_bounds__(256) void k_aggregate(const float* __restrict__ f,
                                                   const float* __restrict__ el,
                                                   const float* __restrict__ er,
                                                   const int* __restrict__ row_ptr,
                                                   const int* __restrict__ csr_src,
                                                   const float* __restrict__ bias,
                                                   float* __restrict__ out, int act) {
  int node = blockIdx.x * 4 + (threadIdx.x >> 6);
  if (node >= NN) return;
  int lane = threadIdx.x & 63;
  int start = row_ptr[node];
  int deg = row_ptr[node + 1] - start;

  float ern = er[node * NH + (lane & 3)];  // er for head (lane&3)

  // pass 1: per-head max (lane handles edge j0+(lane>>2), head lane&3)
  float mm = -INFINITY;
  for (int j0 = 0; j0 < deg; j0 += 16) {
    int j = j0 + (lane >> 2);
    float v = -INFINITY;
    if (j < deg) {
      int s = csr_src[start + j];
      float e = el[s * NH + (lane & 3)] + ern;
      v = (e >= 0.f) ? e : NEG_SLOPE * e;
    }
#pragma unroll
    for (int off = 4; off < 64; off <<= 1) v = fmaxf(v, __shfl_xor(v, off));
    mm = fmaxf(mm, v);
  }
  // pass 2: per-head sum of exp(e - m)
  float ss = 0.f;
  for (int j0 = 0; j0 < deg; j0 += 16) {
    int j = j0 + (lane >> 2);
    float v = 0.f;
    if (j < deg) {
      int s = csr_src[start + j];
      float e = el[s * NH + (lane & 3)] + ern;
      e = (e >= 0.f) ? e : NEG_SLOPE * e;
      v = __expf(e - mm);
    }
#pragma unroll
    for (int off = 4; off < 64; off <<= 1) v += __shfl_xor(v, off);
    ss += v;
  }
  // broadcast m,s for this lane's output head
  int head = lane >> 4;
  float mH = __shfl(mm, head);          // lanes 0..3 hold heads 0..3
  float sH = __shfl(ss, head);
  float erH = __shfl(ern, head);
  float inv = (sH > 0.f) ? (1.f / sH) : 0.f;

  // pass 3: acc = bias + sum alpha * f[src]; lane owns float4 at lane*4
  float4 acc = ((const float4*)bias)[lane];
  for (int j = 0; j < deg; ++j) {
    int s = csr_src[start + j];
    float e = el[s * NH + head] + erH;
    e = (e >= 0.f) ? e : NEG_SLOPE * e;
    float a = __expf(e - mH) * inv;
    float4 fv = ((const float4*)(f + (size_t)s * HD))[lane];
    acc.x = fmaf(a, fv.x, acc.x);
    acc.y = fmaf(a, fv.y, acc.y);
    acc.z = fmaf(a, fv.z, acc.z);
    acc.w = fmaf(a, fv.w, acc.w);
  }
  if (act) {  // ELU (alpha=1)
    acc.x = (acc.x > 0.f) ? acc.x : __expf(acc.x) - 1.f;
    acc.y = (acc.y > 0.f) ? acc.y : __expf(acc.y) - 1.f;
    acc.z = (acc.z > 0.f) ? acc.z : __expf(acc.z) - 1.f;
    acc.w = (acc.w > 0.f) ? acc.w : __expf(acc.w) - 1.f;
  }
  ((float4*)(out + (size_t)node * HD))[lane] = acc;
}

// ============================ launch ============================
extern "C" void kernel_launch(void* const* d_in, const int* in_sizes, int n_in,
                              void* d_out, int out_size, void* d_ws, size_t ws_size,
                              hipStream_t stream) {
  const int* nids = (const int*)d_in[0];
  const int* esrc = (const int*)d_in[1];
  const int* edst = (const int*)d_in[2];
  const float* emb = (const float*)d_in[3];
  const float* W1 = (const float*)d_in[4];
  const float* al1 = (const float*)d_in[5];
  const float* ar1 = (const float*)d_in[6];
  const float* b1 = (const float*)d_in[7];
  const float* W2 = (const float*)d_in[8];
  const float* al2 = (const float*)d_in[9];
  const float* ar2 = (const float*)d_in[10];
  const float* b2 = (const float*)d_in[11];
  float* out = (float*)d_out;

  char* w = (char*)d_ws;
  size_t off = 0;
  float* fbuf = (float*)(w + off); off += (size_t)NN * HD * 4;   // 51.2 MB
  float* el = (float*)(w + off); off += (size_t)NN * NH * 4;
  float* er = (float*)(w + off); off += (size_t)NN * NH * 4;
  int* row_ptr = (int*)(w + off); off += (size_t)(NN + 1) * 4;
  int* counts = (int*)(w + off); off += (size_t)NN * 4;
  int* rank = (int*)(w + off); off += (size_t)EE * 4;
  int* csr_src = (int*)(w + off); off += (size_t)EE * 4;
  int* bsums = (int*)(w + off); off += 1024;

  int nbN = (NN + 255) / 256;   // 196
  int nbE = (EE + 255) / 256;   // 1563

  // CSR build (graph identical for both layers)
  k_zero_i32<<<nbN, 256, 0, stream>>>(counts, NN);
  k_count<<<nbE, 256, 0, stream>>>(edst, counts, rank);
  k_scan1<<<nbN, 256, 0, stream>>>(counts, row_ptr, bsums);
  k_scan2<<<1, 256, 0, stream>>>(bsums, nbN);
  k_scan3<<<nbN, 256, 0, stream>>>(row_ptr, bsums);
  k_scatter<<<nbE, 256, 0, stream>>>(esrc, edst, row_ptr, rank, csr_src);

  dim3 gemm_grid((NN + BM - 1) / BM, HD / BN);
  int nbNode4 = (NN + 3) / 4;   // 12500

  // ---- layer 1 ----  (h goes into d_out, reused as layer-2 input)
  k_gemm<<<gemm_grid, 256, 0, stream>>>(emb, nids, W1, fbuf, NN);
  k_logits<<<nbNode4, 256, 0, stream>>>(fbuf, al1, ar1, el, er);
  k_aggregate<<<nbNode4, 256, 0, stream>>>(fbuf, el, er, row_ptr, csr_src, b1, out, 1);

  // ---- layer 2 ----
  k_gemm<<<gemm_grid, 256, 0, stream>>>(out, nullptr, W2, fbuf, NN);
  k_logits<<<nbNode4, 256, 0, stream>>>(fbuf, al2, ar2, el, er);
  k_aggregate<<<nbNode4, 256, 0, stream>>>(fbuf, el, er, row_ptr, csr_src, b2, out, 0);
}

// Round 2
// 273.527 us; speedup vs baseline: 1.5425x; 1.5425x over previous
//
#include <hip/hip_runtime.h>
#include <math.h>

#define NN 50000
#define EE 400000
#define HD 256
#define NH 4
#define DH 64
#define NEG_SLOPE 0.2f

typedef __attribute__((ext_vector_type(8))) __bf16 bf16x8;
typedef __attribute__((ext_vector_type(4))) float f32x4;

// ============================ CSR build ============================
__global__ void k_zero_i32(int* __restrict__ p, int n) {
  int i = blockIdx.x * blockDim.x + threadIdx.x;
  if (i < n) p[i] = 0;
}

__global__ void k_count(const int* __restrict__ dst, int* __restrict__ counts,
                        int* __restrict__ rank) {
  int e = blockIdx.x * blockDim.x + threadIdx.x;
  if (e < EE) rank[e] = atomicAdd(&counts[dst[e]], 1);
}

__global__ void k_scan1(const int* __restrict__ counts, int* __restrict__ row_ptr,
                        int* __restrict__ bsums) {
  __shared__ int sm[256];
  int i = blockIdx.x * 256 + threadIdx.x;
  int v = (i < NN) ? counts[i] : 0;
  sm[threadIdx.x] = v;
  __syncthreads();
  for (int off = 1; off < 256; off <<= 1) {
    int t = (threadIdx.x >= off) ? sm[threadIdx.x - off] : 0;
    __syncthreads();
    sm[threadIdx.x] += t;
    __syncthreads();
  }
  if (i < NN) row_ptr[i + 1] = sm[threadIdx.x];
  if (threadIdx.x == 255) bsums[blockIdx.x] = sm[255];
}

__global__ void k_scan2(int* __restrict__ bsums, int nb) {
  __shared__ int sm[256];
  int v = (threadIdx.x < nb) ? bsums[threadIdx.x] : 0;
  sm[threadIdx.x] = v;
  __syncthreads();
  for (int off = 1; off < 256; off <<= 1) {
    int t = (threadIdx.x >= off) ? sm[threadIdx.x - off] : 0;
    __syncthreads();
    sm[threadIdx.x] += t;
    __syncthreads();
  }
  if (threadIdx.x < nb) bsums[threadIdx.x] = sm[threadIdx.x] - v;  // exclusive
}

__global__ void k_scan3(int* __restrict__ row_ptr, const int* __restrict__ bsums) {
  int i = blockIdx.x * 256 + threadIdx.x;
  if (i < NN) row_ptr[i + 1] += bsums[blockIdx.x];
  if (blockIdx.x == 0 && threadIdx.x == 0) row_ptr[0] = 0;
}

__global__ void k_scatter(const int* __restrict__ src, const int* __restrict__ dst,
                          const int* __restrict__ row_ptr, const int* __restrict__ rank,
                          int* __restrict__ csr_src) {
  int e = blockIdx.x * blockDim.x + threadIdx.x;
  if (e < EE) csr_src[row_ptr[dst[e]] + rank[e]] = src[e];
}

// ============================ W prep ============================
// Wt_pre layout (bf16): [k_blk 0..7][khalf 0..3][n 0..255][j 0..7]
// element (k,n): offset = (k>>5)*8192 + ((k>>3)&3)*2048 + n*8 + (k&7)
__global__ __launch_bounds__(256) void k_prep_w(const float* __restrict__ W,
                                                __bf16* __restrict__ WtH,
                                                __bf16* __restrict__ WtL) {
  int t = blockIdx.x * 256 + threadIdx.x;  // 65536
  int n = t & 255, k = t >> 8;
  float x = W[(size_t)k * 256 + n];
  __bf16 h = (__bf16)x;
  size_t o = (size_t)(k >> 5) * 8192 + (size_t)((k >> 3) & 3) * 2048 + (size_t)n * 8 + (k & 7);
  WtH[o] = h;
  WtL[o] = (__bf16)(x - (float)h);
}

// ============================ MFMA GEMM ============================
// C[M,256] = A[idx[m],256] @ W ; split-bf16: Ah@Wh + Ah@Wl + Al@Wh
// BM=64, BN=256 (full), BK=32. 4 waves; wave w owns cols [w*64, w*64+64) = head w.
// Fused epilogue: el/er (attention logits) per head.
__device__ __forceinline__ void gload_lds16(const void* g, void* l) {
  __builtin_amdgcn_global_load_lds((const __attribute__((address_space(1))) void*)g,
                                   (__attribute__((address_space(3))) void*)l, 16, 0, 0);
}

__global__ __launch_bounds__(256) void k_gemm_mfma(
    const float* __restrict__ A, const int* __restrict__ idx,
    const __bf16* __restrict__ WtH, const __bf16* __restrict__ WtL,
    const float* __restrict__ al, const float* __restrict__ ar,
    float* __restrict__ C, float* __restrict__ el, float* __restrict__ er,
    int Mrows) {
  // LDS: [khalf 0..3][row/n] of bf16x8 slots
  __shared__ bf16x8 AsH[4 * 64];
  __shared__ bf16x8 AsL[4 * 64];
  __shared__ bf16x8 BsH[4 * 256];
  __shared__ bf16x8 BsL[4 * 256];

  int tid = threadIdx.x;
  int lane = tid & 63;
  int w = tid >> 6;           // wave = head
  int row0 = blockIdx.x * 64;

  f32x4 acc[4][4];
#pragma unroll
  for (int i = 0; i < 4; ++i)
#pragma unroll
    for (int j = 0; j < 4; ++j) acc[i][j] = (f32x4){0.f, 0.f, 0.f, 0.f};

  // A staging mapping: thread -> (khalf = tid&3, row = tid>>2)
  int s_khalf = tid & 3;
  int s_row = tid >> 2;
  int garow = row0 + s_row;
  bool valid = garow < Mrows;
  int arow = valid ? (idx ? idx[garow] : garow) : 0;
  const float* aptr = A + (size_t)arow * HD + s_khalf * 8;

  int khalf = lane >> 4;   // frag k-half
  int l15 = lane & 15;

  for (int kb = 0; kb < 8; ++kb) {
    // ---- stage A (reg: fp32 -> hi/lo bf16) ----
    float x[8];
    if (valid) {
      *(float4*)&x[0] = *(const float4*)(aptr + kb * 32);
      *(float4*)&x[4] = *(const float4*)(aptr + kb * 32 + 4);
    } else {
#pragma unroll
      for (int i = 0; i < 8; ++i) x[i] = 0.f;
    }
    bf16x8 hv, lv;
#pragma unroll
    for (int i = 0; i < 8; ++i) {
      __bf16 h = (__bf16)x[i];
      hv[i] = h;
      lv[i] = (__bf16)(x[i] - (float)h);
    }
    AsH[s_khalf * 64 + s_row] = hv;
    AsL[s_khalf * 64 + s_row] = lv;

    // ---- stage B via global_load_lds (linear, pre-tiled) ----
#pragma unroll
    for (int j = 0; j < 4; ++j) {
      int chunk = w * 4 + j;  // 16 chunks of 64 slots
      size_t goff = (size_t)kb * 8192 + ((size_t)chunk * 64 + lane) * 8;
      gload_lds16(WtH + goff, (void*)&BsH[chunk * 64]);
      gload_lds16(WtL + goff, (void*)&BsL[chunk * 64]);
    }
    __syncthreads();

    // ---- compute ----
    bf16x8 ah[4], alo[4], bh[4], blo[4];
#pragma unroll
    for (int mf = 0; mf < 4; ++mf) {
      ah[mf] = AsH[khalf * 64 + mf * 16 + l15];
      alo[mf] = AsL[khalf * 64 + mf * 16 + l15];
    }
#pragma unroll
    for (int nf = 0; nf < 4; ++nf) {
      int n = w * 64 + nf * 16 + l15;
      bh[nf] = BsH[khalf * 256 + n];
      blo[nf] = BsL[khalf * 256 + n];
    }
#pragma unroll
    for (int mf = 0; mf < 4; ++mf)
#pragma unroll
      for (int nf = 0; nf < 4; ++nf) {
        acc[mf][nf] = __builtin_amdgcn_mfma_f32_16x16x32_bf16(ah[mf], bh[nf], acc[mf][nf], 0, 0, 0);
        acc[mf][nf] = __builtin_amdgcn_mfma_f32_16x16x32_bf16(ah[mf], blo[nf], acc[mf][nf], 0, 0, 0);
        acc[mf][nf] = __builtin_amdgcn_mfma_f32_16x16x32_bf16(alo[mf], bh[nf], acc[mf][nf], 0, 0, 0);
      }
    __syncthreads();
  }

  // ---- epilogue: C store + fused el/er ----
  float alv[4], arv[4];
#pragma unroll
  for (int nf = 0; nf < 4; ++nf) {
    alv[nf] = al[w * 64 + nf * 16 + l15];
    arv[nf] = ar[w * 64 + nf * 16 + l15];
  }
#pragma unroll
  for (int mf = 0; mf < 4; ++mf) {
#pragma unroll
    for (int r = 0; r < 4; ++r) {
      int row = row0 + mf * 16 + (lane >> 4) * 4 + r;
      bool rv = row < Mrows;
      float se = 0.f, sr = 0.f;
#pragma unroll
      for (int nf = 0; nf < 4; ++nf) {
        float v = acc[mf][nf][r];
        se = fmaf(v, alv[nf], se);
        sr = fmaf(v, arv[nf], sr);
        if (rv) C[(size_t)row * HD + w * 64 + nf * 16 + l15] = v;
      }
#pragma unroll
      for (int off = 1; off < 16; off <<= 1) {
        se += __shfl_xor(se, off);
        sr += __shfl_xor(sr, off);
      }
      if (rv && l15 == 0) {
        el[row * NH + w] = se;
        er[row * NH + w] = sr;
      }
    }
  }
}

// ============================ aggregation ============================
__global__ __launch_bounds__(256) void k_aggregate(const float* __restrict__ f,
                                                   const float* __restrict__ el,
                                                   const float* __restrict__ er,
                                                   const int* __restrict__ row_ptr,
                                                   const int* __restrict__ csr_src,
                                                   const float* __restrict__ bias,
                                                   float* __restrict__ out, int act) {
  int node = blockIdx.x * 4 + (threadIdx.x >> 6);
  if (node >= NN) return;
  int lane = threadIdx.x & 63;
  int start = row_ptr[node];
  int deg = row_ptr[node + 1] - start;

  float ern = er[node * NH + (lane & 3)];

  float mm = -INFINITY;
  for (int j0 = 0; j0 < deg; j0 += 16) {
    int j = j0 + (lane >> 2);
    float v = -INFINITY;
    if (j < deg) {
      int s = csr_src[start + j];
      float e = el[s * NH + (lane & 3)] + ern;
      v = (e >= 0.f) ? e : NEG_SLOPE * e;
    }
#pragma unroll
    for (int off = 4; off < 64; off <<= 1) v = fmaxf(v, __shfl_xor(v, off));
    mm = fmaxf(mm, v);
  }
  float ss = 0.f;
  for (int j0 = 0; j0 < deg; j0 += 16) {
    int j = j0 + (lane >> 2);
    float v = 0.f;
    if (j < deg) {
      int s = csr_src[start + j];
      float e = el[s * NH + (lane & 3)] + ern;
      e = (e >= 0.f) ? e : NEG_SLOPE * e;
      v = __expf(e - mm);
    }
#pragma unroll
    for (int off = 4; off < 64; off <<= 1) v += __shfl_xor(v, off);
    ss += v;
  }
  int head = lane >> 4;
  float mH = __shfl(mm, head);
  float sH = __shfl(ss, head);
  float erH = __shfl(ern, head);
  float inv = (sH > 0.f) ? (1.f / sH) : 0.f;

  float4 acc = ((const float4*)bias)[lane];
  for (int j = 0; j < deg; ++j) {
    int s = csr_src[start + j];
    float e = el[s * NH + head] + erH;
    e = (e >= 0.f) ? e : NEG_SLOPE * e;
    float a = __expf(e - mH) * inv;
    float4 fv = ((const float4*)(f + (size_t)s * HD))[lane];
    acc.x = fmaf(a, fv.x, acc.x);
    acc.y = fmaf(a, fv.y, acc.y);
    acc.z = fmaf(a, fv.z, acc.z);
    acc.w = fmaf(a, fv.w, acc.w);
  }
  if (act) {
    acc.x = (acc.x > 0.f) ? acc.x : __expf(acc.x) - 1.f;
    acc.y = (acc.y > 0.f) ? acc.y : __expf(acc.y) - 1.f;
    acc.z = (acc.z > 0.f) ? acc.z : __expf(acc.z) - 1.f;
    acc.w = (acc.w > 0.f) ? acc.w : __expf(acc.w) - 1.f;
  }
  ((float4*)(out + (size_t)node * HD))[lane] = acc;
}

// ============================ launch ============================
extern "C" void kernel_launch(void* const* d_in, const int* in_sizes, int n_in,
                              void* d_out, int out_size, void* d_ws, size_t ws_size,
                              hipStream_t stream) {
  const int* nids = (const int*)d_in[0];
  const int* esrc = (const int*)d_in[1];
  const int* edst = (const int*)d_in[2];
  const float* emb = (const float*)d_in[3];
  const float* W1 = (const float*)d_in[4];
  const float* al1 = (const float*)d_in[5];
  const float* ar1 = (const float*)d_in[6];
  const float* b1 = (const float*)d_in[7];
  const float* W2 = (const float*)d_in[8];
  const float* al2 = (const float*)d_in[9];
  const float* ar2 = (const float*)d_in[10];
  const float* b2 = (const float*)d_in[11];
  float* out = (float*)d_out;

  char* w = (char*)d_ws;
  size_t off = 0;
  float* fbuf = (float*)(w + off); off += (size_t)NN * HD * 4;
  float* el = (float*)(w + off); off += (size_t)NN * NH * 4;
  float* er = (float*)(w + off); off += (size_t)NN * NH * 4;
  int* row_ptr = (int*)(w + off); off += (size_t)(NN + 1) * 4;
  int* counts = (int*)(w + off); off += (size_t)NN * 4;
  int* rank = (int*)(w + off); off += (size_t)EE * 4;
  int* csr_src = (int*)(w + off); off += (size_t)EE * 4;
  int* bsums = (int*)(w + off); off += 1024;
  __bf16* W1tH = (__bf16*)(w + off); off += (size_t)HD * HD * 2;
  __bf16* W1tL = (__bf16*)(w + off); off += (size_t)HD * HD * 2;
  __bf16* W2tH = (__bf16*)(w + off); off += (size_t)HD * HD * 2;
  __bf16* W2tL = (__bf16*)(w + off); off += (size_t)HD * HD * 2;

  int nbN = (NN + 255) / 256;
  int nbE = (EE + 255) / 256;

  // CSR build + W prep (graph/W identical across layers)
  k_zero_i32<<<nbN, 256, 0, stream>>>(counts, NN);
  k_count<<<nbE, 256, 0, stream>>>(edst, counts, rank);
  k_scan1<<<nbN, 256, 0, stream>>>(counts, row_ptr, bsums);
  k_scan2<<<1, 256, 0, stream>>>(bsums, nbN);
  k_scan3<<<nbN, 256, 0, stream>>>(row_ptr, bsums);
  k_scatter<<<nbE, 256, 0, stream>>>(esrc, edst, row_ptr, rank, csr_src);
  k_prep_w<<<256, 256, 0, stream>>>(W1, W1tH, W1tL);
  k_prep_w<<<256, 256, 0, stream>>>(W2, W2tH, W2tL);

  int gemm_grid = (NN + 63) / 64;  // 782
  int nbNode4 = (NN + 3) / 4;

  // ---- layer 1 ----
  k_gemm_mfma<<<gemm_grid, 256, 0, stream>>>(emb, nids, W1tH, W1tL, al1, ar1,
                                             fbuf, el, er, NN);
  k_aggregate<<<nbNode4, 256, 0, stream>>>(fbuf, el, er, row_ptr, csr_src, b1, out, 1);

  // ---- layer 2 ----
  k_gemm_mfma<<<gemm_grid, 256, 0, stream>>>(out, nullptr, W2tH, W2tL, al2, ar2,
                                             fbuf, el, er, NN);
  k_aggregate<<<nbNode4, 256, 0, stream>>>(fbuf, el, er, row_ptr, csr_src, b2, out, 0);
}

// Round 3
// 218.080 us; speedup vs baseline: 1.9347x; 1.2543x over previous
//
#include <hip/hip_runtime.h>
#include <math.h>

#define NN 50000
#define EE 400000
#define HD 256
#define NH 4
#define DH 64
#define NEG_SLOPE 0.2f

typedef __attribute__((ext_vector_type(8))) __bf16 bf16x8;
typedef __attribute__((ext_vector_type(4))) float f32x4;

__device__ __forceinline__ float bf2f(unsigned short h) {
  return __uint_as_float(((unsigned)h) << 16);
}

// ============================ CSR build ============================
__global__ void k_zero_i32(int* __restrict__ p, int n) {
  int i = blockIdx.x * blockDim.x + threadIdx.x;
  if (i < n) p[i] = 0;
}

__global__ void k_count(const int* __restrict__ dst, int* __restrict__ counts,
                        int* __restrict__ rank) {
  int e = blockIdx.x * blockDim.x + threadIdx.x;
  if (e < EE) rank[e] = atomicAdd(&counts[dst[e]], 1);
}

__global__ void k_scan1(const int* __restrict__ counts, int* __restrict__ row_ptr,
                        int* __restrict__ bsums) {
  __shared__ int sm[256];
  int i = blockIdx.x * 256 + threadIdx.x;
  int v = (i < NN) ? counts[i] : 0;
  sm[threadIdx.x] = v;
  __syncthreads();
  for (int off = 1; off < 256; off <<= 1) {
    int t = (threadIdx.x >= off) ? sm[threadIdx.x - off] : 0;
    __syncthreads();
    sm[threadIdx.x] += t;
    __syncthreads();
  }
  if (i < NN) row_ptr[i + 1] = sm[threadIdx.x];
  if (threadIdx.x == 255) bsums[blockIdx.x] = sm[255];
}

__global__ void k_scan2(int* __restrict__ bsums, int nb) {
  __shared__ int sm[256];
  int v = (threadIdx.x < nb) ? bsums[threadIdx.x] : 0;
  sm[threadIdx.x] = v;
  __syncthreads();
  for (int off = 1; off < 256; off <<= 1) {
    int t = (threadIdx.x >= off) ? sm[threadIdx.x - off] : 0;
    __syncthreads();
    sm[threadIdx.x] += t;
    __syncthreads();
  }
  if (threadIdx.x < nb) bsums[threadIdx.x] = sm[threadIdx.x] - v;  // exclusive
}

__global__ void k_scan3(int* __restrict__ row_ptr, const int* __restrict__ bsums) {
  int i = blockIdx.x * 256 + threadIdx.x;
  if (i < NN) row_ptr[i + 1] += bsums[blockIdx.x];
  if (blockIdx.x == 0 && threadIdx.x == 0) row_ptr[0] = 0;
}

__global__ void k_scatter(const int* __restrict__ src, const int* __restrict__ dst,
                          const int* __restrict__ row_ptr, const int* __restrict__ rank,
                          int* __restrict__ csr_src) {
  int e = blockIdx.x * blockDim.x + threadIdx.x;
  if (e < EE) csr_src[row_ptr[dst[e]] + rank[e]] = src[e];
}

// ============================ W prep ============================
// Wt_pre layout (bf16): [k_blk 0..7][khalf 0..3][n 0..255][j 0..7]
__global__ __launch_bounds__(256) void k_prep_w(const float* __restrict__ W,
                                                __bf16* __restrict__ WtH,
                                                __bf16* __restrict__ WtL) {
  int t = blockIdx.x * 256 + threadIdx.x;  // 65536
  int n = t & 255, k = t >> 8;
  float x = W[(size_t)k * 256 + n];
  __bf16 h = (__bf16)x;
  size_t o = (size_t)(k >> 5) * 8192 + (size_t)((k >> 3) & 3) * 2048 + (size_t)n * 8 + (k & 7);
  WtH[o] = h;
  WtL[o] = (__bf16)(x - (float)h);
}

// ============================ MFMA GEMM ============================
// f[M,256](bf16) = A[idx[m],256] @ W ; split-bf16: Ah@Wh + Ah@Wl + Al@Wh
// Fused epilogue: el/er logits from fp32 accumulators.
__device__ __forceinline__ void gload_lds16(const void* g, void* l) {
  __builtin_amdgcn_global_load_lds((const __attribute__((address_space(1))) void*)g,
                                   (__attribute__((address_space(3))) void*)l, 16, 0, 0);
}

__global__ __launch_bounds__(256) void k_gemm_mfma(
    const float* __restrict__ A, const int* __restrict__ idx,
    const __bf16* __restrict__ WtH, const __bf16* __restrict__ WtL,
    const float* __restrict__ al, const float* __restrict__ ar,
    __bf16* __restrict__ C, float* __restrict__ el, float* __restrict__ er,
    int Mrows) {
  __shared__ bf16x8 AsH[4 * 64];
  __shared__ bf16x8 AsL[4 * 64];
  __shared__ bf16x8 BsH[4 * 256];
  __shared__ bf16x8 BsL[4 * 256];

  int tid = threadIdx.x;
  int lane = tid & 63;
  int w = tid >> 6;           // wave = head
  int row0 = blockIdx.x * 64;

  f32x4 acc[4][4];
#pragma unroll
  for (int i = 0; i < 4; ++i)
#pragma unroll
    for (int j = 0; j < 4; ++j) acc[i][j] = (f32x4){0.f, 0.f, 0.f, 0.f};

  int s_khalf = tid & 3;
  int s_row = tid >> 2;
  int garow = row0 + s_row;
  bool valid = garow < Mrows;
  int arow = valid ? (idx ? idx[garow] : garow) : 0;
  const float* aptr = A + (size_t)arow * HD + s_khalf * 8;

  int khalf = lane >> 4;
  int l15 = lane & 15;

  for (int kb = 0; kb < 8; ++kb) {
    float x[8];
    if (valid) {
      *(float4*)&x[0] = *(const float4*)(aptr + kb * 32);
      *(float4*)&x[4] = *(const float4*)(aptr + kb * 32 + 4);
    } else {
#pragma unroll
      for (int i = 0; i < 8; ++i) x[i] = 0.f;
    }
    bf16x8 hv, lv;
#pragma unroll
    for (int i = 0; i < 8; ++i) {
      __bf16 h = (__bf16)x[i];
      hv[i] = h;
      lv[i] = (__bf16)(x[i] - (float)h);
    }
    AsH[s_khalf * 64 + s_row] = hv;
    AsL[s_khalf * 64 + s_row] = lv;

#pragma unroll
    for (int j = 0; j < 4; ++j) {
      int chunk = w * 4 + j;
      size_t goff = (size_t)kb * 8192 + ((size_t)chunk * 64 + lane) * 8;
      gload_lds16(WtH + goff, (void*)&BsH[chunk * 64]);
      gload_lds16(WtL + goff, (void*)&BsL[chunk * 64]);
    }
    __syncthreads();

    bf16x8 ah[4], alo[4], bh[4], blo[4];
#pragma unroll
    for (int mf = 0; mf < 4; ++mf) {
      ah[mf] = AsH[khalf * 64 + mf * 16 + l15];
      alo[mf] = AsL[khalf * 64 + mf * 16 + l15];
    }
#pragma unroll
    for (int nf = 0; nf < 4; ++nf) {
      int n = w * 64 + nf * 16 + l15;
      bh[nf] = BsH[khalf * 256 + n];
      blo[nf] = BsL[khalf * 256 + n];
    }
#pragma unroll
    for (int mf = 0; mf < 4; ++mf)
#pragma unroll
      for (int nf = 0; nf < 4; ++nf) {
        acc[mf][nf] = __builtin_amdgcn_mfma_f32_16x16x32_bf16(ah[mf], bh[nf], acc[mf][nf], 0, 0, 0);
        acc[mf][nf] = __builtin_amdgcn_mfma_f32_16x16x32_bf16(ah[mf], blo[nf], acc[mf][nf], 0, 0, 0);
        acc[mf][nf] = __builtin_amdgcn_mfma_f32_16x16x32_bf16(alo[mf], bh[nf], acc[mf][nf], 0, 0, 0);
      }
    __syncthreads();
  }

  // ---- epilogue: bf16 C store + fused el/er ----
  float alv[4], arv[4];
#pragma unroll
  for (int nf = 0; nf < 4; ++nf) {
    alv[nf] = al[w * 64 + nf * 16 + l15];
    arv[nf] = ar[w * 64 + nf * 16 + l15];
  }
#pragma unroll
  for (int mf = 0; mf < 4; ++mf) {
#pragma unroll
    for (int r = 0; r < 4; ++r) {
      int row = row0 + mf * 16 + (lane >> 4) * 4 + r;
      bool rv = row < Mrows;
      float se = 0.f, sr = 0.f;
#pragma unroll
      for (int nf = 0; nf < 4; ++nf) {
        float v = acc[mf][nf][r];
        se = fmaf(v, alv[nf], se);
        sr = fmaf(v, arv[nf], sr);
        if (rv) C[(size_t)row * HD + w * 64 + nf * 16 + l15] = (__bf16)v;
      }
#pragma unroll
      for (int off = 1; off < 16; off <<= 1) {
        se += __shfl_xor(se, off);
        sr += __shfl_xor(sr, off);
      }
      if (rv && l15 == 0) {
        el[row * NH + w] = se;
        er[row * NH + w] = sr;
      }
    }
  }
}

// ============================ aggregation ============================
// One wave per dst node. deg<=64: csr/logits cached in regs, alpha via
// bpermute; the f-gather is the ONLY memory op in the accumulate loop.
__global__ __launch_bounds__(256) void k_aggregate(const __bf16* __restrict__ f,
                                                   const float* __restrict__ el,
                                                   const float* __restrict__ er,
                                                   const int* __restrict__ row_ptr,
                                                   const int* __restrict__ csr_src,
                                                   const float* __restrict__ bias,
                                                   float* __restrict__ out, int act) {
  int node = blockIdx.x * 4 + (threadIdx.x >> 6);
  if (node >= NN) return;
  int lane = threadIdx.x & 63;
  int start = row_ptr[node];
  int deg = row_ptr[node + 1] - start;

  float ern = er[node * NH + (lane & 3)];

  // chunks 0..3 (edges 0..63): lane handles edge c*16+(lane>>2), head lane&3
  int sreg[4];
  float ereg[4];
  float mloc = -INFINITY;
#pragma unroll
  for (int c = 0; c < 4; ++c) {
    int j = c * 16 + (lane >> 2);
    int s = 0;
    float e = -INFINITY;
    if (c * 16 < deg && j < deg) {
      s = csr_src[start + j];
      e = el[s * NH + (lane & 3)] + ern;
      e = (e >= 0.f) ? e : NEG_SLOPE * e;
    }
    sreg[c] = s;
    ereg[c] = e;
    mloc = fmaxf(mloc, e);
  }
  // rare tail (deg>64): fold max with loads
  for (int j0 = 64; j0 < deg; j0 += 16) {
    int j = j0 + (lane >> 2);
    if (j < deg) {
      int s = csr_src[start + j];
      float e = el[s * NH + (lane & 3)] + ern;
      e = (e >= 0.f) ? e : NEG_SLOPE * e;
      mloc = fmaxf(mloc, e);
    }
  }
  float mm = mloc;
#pragma unroll
  for (int off = 4; off < 64; off <<= 1) mm = fmaxf(mm, __shfl_xor(mm, off));

  // exp + sum
  float vreg[4];
  float vloc = 0.f;
#pragma unroll
  for (int c = 0; c < 4; ++c) {
    float v = (ereg[c] > -INFINITY) ? __expf(ereg[c] - mm) : 0.f;
    vreg[c] = v;
    vloc += v;
  }
  for (int j0 = 64; j0 < deg; j0 += 16) {
    int j = j0 + (lane >> 2);
    if (j < deg) {
      int s = csr_src[start + j];
      float e = el[s * NH + (lane & 3)] + ern;
      e = (e >= 0.f) ? e : NEG_SLOPE * e;
      vloc += __expf(e - mm);
    }
  }
  float ss = vloc;
#pragma unroll
  for (int off = 4; off < 64; off <<= 1) ss += __shfl_xor(ss, off);

  float inv_own = (ss > 0.f) ? (1.f / ss) : 0.f;
  float areg[4];
#pragma unroll
  for (int c = 0; c < 4; ++c) areg[c] = vreg[c] * inv_own;

  int head = lane >> 4;

  // accumulate: lane owns f32x4 at cols lane*4..lane*4+3
  float4 acc = ((const float4*)bias)[lane];
#pragma unroll 1
  for (int c = 0; c < 4; ++c) {
    if (c * 16 < deg) {
      int je = deg - c * 16;
      je = (je > 16) ? 16 : je;
      for (int jj = 0; jj < je; ++jj) {
        int srcl = jj * 4 + head;
        int s = __shfl(sreg[c], srcl);
        float a = __shfl(areg[c], srcl);
        ushort4 u = ((const ushort4*)(f + (size_t)s * HD))[lane];
        acc.x = fmaf(a, bf2f(u.x), acc.x);
        acc.y = fmaf(a, bf2f(u.y), acc.y);
        acc.z = fmaf(a, bf2f(u.z), acc.z);
        acc.w = fmaf(a, bf2f(u.w), acc.w);
      }
    }
  }
  // rare tail (deg>64)
  if (deg > 64) {
    float mH = __shfl(mm, head);
    float sH = __shfl(ss, head);
    float erH = __shfl(ern, head);
    float invH = (sH > 0.f) ? (1.f / sH) : 0.f;
    for (int j = 64; j < deg; ++j) {
      int s = csr_src[start + j];
      float e = el[s * NH + head] + erH;
      e = (e >= 0.f) ? e : NEG_SLOPE * e;
      float a = __expf(e - mH) * invH;
      ushort4 u = ((const ushort4*)(f + (size_t)s * HD))[lane];
      acc.x = fmaf(a, bf2f(u.x), acc.x);
      acc.y = fmaf(a, bf2f(u.y), acc.y);
      acc.z = fmaf(a, bf2f(u.z), acc.z);
      acc.w = fmaf(a, bf2f(u.w), acc.w);
    }
  }

  if (act) {
    acc.x = (acc.x > 0.f) ? acc.x : __expf(acc.x) - 1.f;
    acc.y = (acc.y > 0.f) ? acc.y : __expf(acc.y) - 1.f;
    acc.z = (acc.z > 0.f) ? acc.z : __expf(acc.z) - 1.f;
    acc.w = (acc.w > 0.f) ? acc.w : __expf(acc.w) - 1.f;
  }
  ((float4*)(out + (size_t)node * HD))[lane] = acc;
}

// ============================ launch ============================
extern "C" void kernel_launch(void* const* d_in, const int* in_sizes, int n_in,
                              void* d_out, int out_size, void* d_ws, size_t ws_size,
                              hipStream_t stream) {
  const int* nids = (const int*)d_in[0];
  const int* esrc = (const int*)d_in[1];
  const int* edst = (const int*)d_in[2];
  const float* emb = (const float*)d_in[3];
  const float* W1 = (const float*)d_in[4];
  const float* al1 = (const float*)d_in[5];
  const float* ar1 = (const float*)d_in[6];
  const float* b1 = (const float*)d_in[7];
  const float* W2 = (const float*)d_in[8];
  const float* al2 = (const float*)d_in[9];
  const float* ar2 = (const float*)d_in[10];
  const float* b2 = (const float*)d_in[11];
  float* out = (float*)d_out;

  char* w = (char*)d_ws;
  size_t off = 0;
  __bf16* fbuf = (__bf16*)(w + off); off += (size_t)NN * HD * 2;
  float* el = (float*)(w + off); off += (size_t)NN * NH * 4;
  float* er = (float*)(w + off); off += (size_t)NN * NH * 4;
  int* row_ptr = (int*)(w + off); off += (size_t)(NN + 1) * 4;
  int* counts = (int*)(w + off); off += (size_t)NN * 4;
  int* rank = (int*)(w + off); off += (size_t)EE * 4;
  int* csr_src = (int*)(w + off); off += (size_t)EE * 4;
  int* bsums = (int*)(w + off); off += 1024;
  __bf16* W1tH = (__bf16*)(w + off); off += (size_t)HD * HD * 2;
  __bf16* W1tL = (__bf16*)(w + off); off += (size_t)HD * HD * 2;
  __bf16* W2tH = (__bf16*)(w + off); off += (size_t)HD * HD * 2;
  __bf16* W2tL = (__bf16*)(w + off); off += (size_t)HD * HD * 2;

  int nbN = (NN + 255) / 256;
  int nbE = (EE + 255) / 256;

  k_zero_i32<<<nbN, 256, 0, stream>>>(counts, NN);
  k_count<<<nbE, 256, 0, stream>>>(edst, counts, rank);
  k_scan1<<<nbN, 256, 0, stream>>>(counts, row_ptr, bsums);
  k_scan2<<<1, 256, 0, stream>>>(bsums, nbN);
  k_scan3<<<nbN, 256, 0, stream>>>(row_ptr, bsums);
  k_scatter<<<nbE, 256, 0, stream>>>(esrc, edst, row_ptr, rank, csr_src);
  k_prep_w<<<256, 256, 0, stream>>>(W1, W1tH, W1tL);
  k_prep_w<<<256, 256, 0, stream>>>(W2, W2tH, W2tL);

  int gemm_grid = (NN + 63) / 64;
  int nbNode4 = (NN + 3) / 4;

  // ---- layer 1 ----
  k_gemm_mfma<<<gemm_grid, 256, 0, stream>>>(emb, nids, W1tH, W1tL, al1, ar1,
                                             fbuf, el, er, NN);
  k_aggregate<<<nbNode4, 256, 0, stream>>>(fbuf, el, er, row_ptr, csr_src, b1, out, 1);

  // ---- layer 2 ----
  k_gemm_mfma<<<gemm_grid, 256, 0, stream>>>(out, nullptr, W2tH, W2tL, al2, ar2,
                                             fbuf, el, er, NN);
  k_aggregate<<<nbNode4, 256, 0, stream>>>(fbuf, el, er, row_ptr, csr_src, b2, out, 0);
}

// Round 4
// 199.167 us; speedup vs baseline: 2.1185x; 1.0950x over previous
//
#include <hip/hip_runtime.h>
#include <math.h>

#define NN 50000
#define EE 400000
#define HD 256
#define NH 4
#define DH 64
#define NEG_SLOPE 0.2f

typedef __attribute__((ext_vector_type(8))) __bf16 bf16x8;
typedef __attribute__((ext_vector_type(4))) float f32x4;

__device__ __forceinline__ float bf2f(unsigned short h) {
  return __uint_as_float(((unsigned)h) << 16);
}

// ============================ CSR build ============================
__global__ void k_zero_i32(int* __restrict__ p, int n) {
  int i = blockIdx.x * blockDim.x + threadIdx.x;
  if (i < n) p[i] = 0;
}

__global__ void k_count(const int* __restrict__ dst, int* __restrict__ counts,
                        int* __restrict__ rank) {
  int e = blockIdx.x * blockDim.x + threadIdx.x;
  if (e < EE) rank[e] = atomicAdd(&counts[dst[e]], 1);
}

__global__ void k_scan1(const int* __restrict__ counts, int* __restrict__ row_ptr,
                        int* __restrict__ bsums) {
  __shared__ int sm[256];
  int i = blockIdx.x * 256 + threadIdx.x;
  int v = (i < NN) ? counts[i] : 0;
  sm[threadIdx.x] = v;
  __syncthreads();
  for (int off = 1; off < 256; off <<= 1) {
    int t = (threadIdx.x >= off) ? sm[threadIdx.x - off] : 0;
    __syncthreads();
    sm[threadIdx.x] += t;
    __syncthreads();
  }
  if (i < NN) row_ptr[i + 1] = sm[threadIdx.x];
  if (threadIdx.x == 255) bsums[blockIdx.x] = sm[255];
}

__global__ void k_scan2(int* __restrict__ bsums, int nb) {
  __shared__ int sm[256];
  int v = (threadIdx.x < nb) ? bsums[threadIdx.x] : 0;
  sm[threadIdx.x] = v;
  __syncthreads();
  for (int off = 1; off < 256; off <<= 1) {
    int t = (threadIdx.x >= off) ? sm[threadIdx.x - off] : 0;
    __syncthreads();
    sm[threadIdx.x] += t;
    __syncthreads();
  }
  if (threadIdx.x < nb) bsums[threadIdx.x] = sm[threadIdx.x] - v;  // exclusive
}

__global__ void k_scan3(int* __restrict__ row_ptr, const int* __restrict__ bsums) {
  int i = blockIdx.x * 256 + threadIdx.x;
  if (i < NN) row_ptr[i + 1] += bsums[blockIdx.x];
  if (blockIdx.x == 0 && threadIdx.x == 0) row_ptr[0] = 0;
}

__global__ void k_scatter(const int* __restrict__ src, const int* __restrict__ dst,
                          const int* __restrict__ row_ptr, const int* __restrict__ rank,
                          int* __restrict__ csr_src) {
  int e = blockIdx.x * blockDim.x + threadIdx.x;
  if (e < EE) csr_src[row_ptr[dst[e]] + rank[e]] = src[e];
}

// ============================ W prep ============================
// Wt_pre layout (bf16): [k_blk 0..7][khalf 0..3][n 0..255][j 0..7]
__global__ __launch_bounds__(256) void k_prep_w2(const float* __restrict__ W1,
                                                 const float* __restrict__ W2,
                                                 __bf16* __restrict__ W1H,
                                                 __bf16* __restrict__ W1L,
                                                 __bf16* __restrict__ W2H,
                                                 __bf16* __restrict__ W2L) {
  int b = blockIdx.x;
  const float* W = (b < 256) ? W1 : W2;
  __bf16* WH = (b < 256) ? W1H : W2H;
  __bf16* WL = (b < 256) ? W1L : W2L;
  int t = (b & 255) * 256 + threadIdx.x;  // 65536
  int n = t & 255, k = t >> 8;
  float x = W[(size_t)k * 256 + n];
  __bf16 h = (__bf16)x;
  size_t o = (size_t)(k >> 5) * 8192 + (size_t)((k >> 3) & 3) * 2048 + (size_t)n * 8 + (k & 7);
  WH[o] = h;
  WL[o] = (__bf16)(x - (float)h);
}

// ============================ MFMA GEMM ============================
// f[M,256](bf16) = A[idx[m],256] @ W ; split-bf16: Ah@Wh + Ah@Wl + Al@Wh
// 2-phase overlap: stage kb+1 (global) is issued BEFORE kb's MFMA section,
// so loads get the MFMA duration to land before the barrier drain.
__device__ __forceinline__ void gload_lds16(const void* g, void* l) {
  __builtin_amdgcn_global_load_lds((const __attribute__((address_space(1))) void*)g,
                                   (__attribute__((address_space(3))) void*)l, 16, 0, 0);
}

__global__ __launch_bounds__(256) void k_gemm_mfma(
    const float* __restrict__ A, const int* __restrict__ idx,
    const __bf16* __restrict__ WtH, const __bf16* __restrict__ WtL,
    const float* __restrict__ al, const float* __restrict__ ar,
    __bf16* __restrict__ C, float* __restrict__ el, float* __restrict__ er,
    int Mrows) {
  __shared__ bf16x8 AsH[4 * 64];
  __shared__ bf16x8 AsL[4 * 64];
  __shared__ bf16x8 BsH[4 * 256];
  __shared__ bf16x8 BsL[4 * 256];

  int tid = threadIdx.x;
  int lane = tid & 63;
  int w = tid >> 6;           // wave = head
  int row0 = blockIdx.x * 64;

  f32x4 acc[4][4];
#pragma unroll
  for (int i = 0; i < 4; ++i)
#pragma unroll
    for (int j = 0; j < 4; ++j) acc[i][j] = (f32x4){0.f, 0.f, 0.f, 0.f};

  int s_khalf = tid & 3;
  int s_row = tid >> 2;
  int garow = row0 + s_row;
  bool valid = garow < Mrows;
  int arow = valid ? (idx ? idx[garow] : garow) : 0;
  const float* aptr = A + (size_t)arow * HD + s_khalf * 8;

  int khalf = lane >> 4;
  int l15 = lane & 15;

  // ---- prologue: stage kb=0 ----
  float x[8];
  if (valid) {
    *(float4*)&x[0] = *(const float4*)(aptr);
    *(float4*)&x[4] = *(const float4*)(aptr + 4);
  } else {
#pragma unroll
    for (int i = 0; i < 8; ++i) x[i] = 0.f;
  }
#pragma unroll
  for (int j = 0; j < 4; ++j) {
    int chunk = w * 4 + j;
    size_t goff = ((size_t)chunk * 64 + lane) * 8;
    gload_lds16(WtH + goff, (void*)&BsH[chunk * 64]);
    gload_lds16(WtL + goff, (void*)&BsL[chunk * 64]);
  }
  {
    bf16x8 hv, lv;
#pragma unroll
    for (int i = 0; i < 8; ++i) {
      __bf16 h = (__bf16)x[i];
      hv[i] = h;
      lv[i] = (__bf16)(x[i] - (float)h);
    }
    AsH[s_khalf * 64 + s_row] = hv;
    AsL[s_khalf * 64 + s_row] = lv;
  }
  __syncthreads();

  for (int kb = 0; kb < 8; ++kb) {
    // ---- read kb frags into regs ----
    bf16x8 ah[4], alo[4], bh[4], blo[4];
#pragma unroll
    for (int mf = 0; mf < 4; ++mf) {
      ah[mf] = AsH[khalf * 64 + mf * 16 + l15];
      alo[mf] = AsL[khalf * 64 + mf * 16 + l15];
    }
#pragma unroll
    for (int nf = 0; nf < 4; ++nf) {
      int n = w * 64 + nf * 16 + l15;
      bh[nf] = BsH[khalf * 256 + n];
      blo[nf] = BsL[khalf * 256 + n];
    }
    __syncthreads();  // all waves done reading; safe to restage

    // ---- issue kb+1 global loads (overlap with MFMA below) ----
    if (kb < 7) {
      if (valid) {
        *(float4*)&x[0] = *(const float4*)(aptr + (kb + 1) * 32);
        *(float4*)&x[4] = *(const float4*)(aptr + (kb + 1) * 32 + 4);
      }
#pragma unroll
      for (int j = 0; j < 4; ++j) {
        int chunk = w * 4 + j;
        size_t goff = (size_t)(kb + 1) * 8192 + ((size_t)chunk * 64 + lane) * 8;
        gload_lds16(WtH + goff, (void*)&BsH[chunk * 64]);
        gload_lds16(WtL + goff, (void*)&BsL[chunk * 64]);
      }
    }

    // ---- MFMA (operands in regs) ----
#pragma unroll
    for (int mf = 0; mf < 4; ++mf)
#pragma unroll
      for (int nf = 0; nf < 4; ++nf) {
        acc[mf][nf] = __builtin_amdgcn_mfma_f32_16x16x32_bf16(ah[mf], bh[nf], acc[mf][nf], 0, 0, 0);
        acc[mf][nf] = __builtin_amdgcn_mfma_f32_16x16x32_bf16(ah[mf], blo[nf], acc[mf][nf], 0, 0, 0);
        acc[mf][nf] = __builtin_amdgcn_mfma_f32_16x16x32_bf16(alo[mf], bh[nf], acc[mf][nf], 0, 0, 0);
      }

    // ---- finish A staging for kb+1 ----
    if (kb < 7) {
      bf16x8 hv, lv;
#pragma unroll
      for (int i = 0; i < 8; ++i) {
        __bf16 h = (__bf16)x[i];
        hv[i] = h;
        lv[i] = (__bf16)(x[i] - (float)h);
      }
      AsH[s_khalf * 64 + s_row] = hv;
      AsL[s_khalf * 64 + s_row] = lv;
    }
    __syncthreads();
  }

  // ---- epilogue: bf16 C store + fused el/er ----
  float alv[4], arv[4];
#pragma unroll
  for (int nf = 0; nf < 4; ++nf) {
    alv[nf] = al[w * 64 + nf * 16 + l15];
    arv[nf] = ar[w * 64 + nf * 16 + l15];
  }
#pragma unroll
  for (int mf = 0; mf < 4; ++mf) {
#pragma unroll
    for (int r = 0; r < 4; ++r) {
      int row = row0 + mf * 16 + (lane >> 4) * 4 + r;
      bool rv = row < Mrows;
      float se = 0.f, sr = 0.f;
#pragma unroll
      for (int nf = 0; nf < 4; ++nf) {
        float v = acc[mf][nf][r];
        se = fmaf(v, alv[nf], se);
        sr = fmaf(v, arv[nf], sr);
        if (rv) C[(size_t)row * HD + w * 64 + nf * 16 + l15] = (__bf16)v;
      }
#pragma unroll
      for (int off = 1; off < 16; off <<= 1) {
        se += __shfl_xor(se, off);
        sr += __shfl_xor(sr, off);
      }
      if (rv && l15 == 0) {
        el[row * NH + w] = se;
        er[row * NH + w] = sr;
      }
    }
  }
}

// ============================ aggregation ============================
// One wave per dst node; 8-deep batched gather in the accumulate loop.
__global__ __launch_bounds__(256) void k_aggregate(const __bf16* __restrict__ f,
                                                   const float* __restrict__ el,
                                                   const float* __restrict__ er,
                                                   const int* __restrict__ row_ptr,
                                                   const int* __restrict__ csr_src,
                                                   const float* __restrict__ bias,
                                                   float* __restrict__ out, int act) {
  int node = blockIdx.x * 4 + (threadIdx.x >> 6);
  if (node >= NN) return;
  int lane = threadIdx.x & 63;
  int start = row_ptr[node];
  int deg = row_ptr[node + 1] - start;

  float ern = er[node * NH + (lane & 3)];

  // chunks 0..3 (edges 0..63): lane handles edge c*16+(lane>>2), head lane&3
  int sreg[4];
  float ereg[4];
  float mloc = -INFINITY;
#pragma unroll
  for (int c = 0; c < 4; ++c) {
    int j = c * 16 + (lane >> 2);
    int s = 0;
    float e = -INFINITY;
    if (c * 16 < deg && j < deg) {
      s = csr_src[start + j];
      e = el[s * NH + (lane & 3)] + ern;
      e = (e >= 0.f) ? e : NEG_SLOPE * e;
    }
    sreg[c] = s;
    ereg[c] = e;
    mloc = fmaxf(mloc, e);
  }
  for (int j0 = 64; j0 < deg; j0 += 16) {  // rare tail
    int j = j0 + (lane >> 2);
    if (j < deg) {
      int s = csr_src[start + j];
      float e = el[s * NH + (lane & 3)] + ern;
      e = (e >= 0.f) ? e : NEG_SLOPE * e;
      mloc = fmaxf(mloc, e);
    }
  }
  float mm = mloc;
#pragma unroll
  for (int off = 4; off < 64; off <<= 1) mm = fmaxf(mm, __shfl_xor(mm, off));

  float vreg[4];
  float vloc = 0.f;
#pragma unroll
  for (int c = 0; c < 4; ++c) {
    float v = (ereg[c] > -INFINITY) ? __expf(ereg[c] - mm) : 0.f;
    vreg[c] = v;
    vloc += v;
  }
  for (int j0 = 64; j0 < deg; j0 += 16) {  // rare tail
    int j = j0 + (lane >> 2);
    if (j < deg) {
      int s = csr_src[start + j];
      float e = el[s * NH + (lane & 3)] + ern;
      e = (e >= 0.f) ? e : NEG_SLOPE * e;
      vloc += __expf(e - mm);
    }
  }
  float ss = vloc;
#pragma unroll
  for (int off = 4; off < 64; off <<= 1) ss += __shfl_xor(ss, off);

  float inv_own = (ss > 0.f) ? (1.f / ss) : 0.f;
  float areg[4];
#pragma unroll
  for (int c = 0; c < 4; ++c) areg[c] = vreg[c] * inv_own;

  int head = lane >> 4;

  // accumulate: lane owns f32x4 at cols lane*4..lane*4+3; 8-deep load batches
  float4 acc = ((const float4*)bias)[lane];
  for (int c = 0; c < 4; ++c) {
    int base = c * 16;
    if (base >= deg) break;
    int cnt = deg - base;
    cnt = (cnt > 16) ? 16 : cnt;
    for (int g = 0; g < cnt; g += 8) {
      ushort4 u[8];
      float aa[8];
#pragma unroll
      for (int jj = 0; jj < 8; ++jj) {
        int j = g + jj;
        int jc = (j < cnt) ? j : (cnt - 1);   // clamp: duplicate row, a=0
        int srcl = jc * 4 + head;
        int s = __shfl(sreg[c], srcl);
        float a = __shfl(areg[c], srcl);
        aa[jj] = (j < cnt) ? a : 0.f;
        u[jj] = ((const ushort4*)(f + (size_t)s * HD))[lane];
      }
#pragma unroll
      for (int jj = 0; jj < 8; ++jj) {
        acc.x = fmaf(aa[jj], bf2f(u[jj].x), acc.x);
        acc.y = fmaf(aa[jj], bf2f(u[jj].y), acc.y);
        acc.z = fmaf(aa[jj], bf2f(u[jj].z), acc.z);
        acc.w = fmaf(aa[jj], bf2f(u[jj].w), acc.w);
      }
    }
  }
  // rare tail (deg>64)
  if (deg > 64) {
    float mH = __shfl(mm, head);
    float sH = __shfl(ss, head);
    float erH = __shfl(ern, head);
    float invH = (sH > 0.f) ? (1.f / sH) : 0.f;
    for (int j = 64; j < deg; ++j) {
      int s = csr_src[start + j];
      float e = el[s * NH + head] + erH;
      e = (e >= 0.f) ? e : NEG_SLOPE * e;
      float a = __expf(e - mH) * invH;
      ushort4 u = ((const ushort4*)(f + (size_t)s * HD))[lane];
      acc.x = fmaf(a, bf2f(u.x), acc.x);
      acc.y = fmaf(a, bf2f(u.y), acc.y);
      acc.z = fmaf(a, bf2f(u.z), acc.z);
      acc.w = fmaf(a, bf2f(u.w), acc.w);
    }
  }

  if (act) {
    acc.x = (acc.x > 0.f) ? acc.x : __expf(acc.x) - 1.f;
    acc.y = (acc.y > 0.f) ? acc.y : __expf(acc.y) - 1.f;
    acc.z = (acc.z > 0.f) ? acc.z : __expf(acc.z) - 1.f;
    acc.w = (acc.w > 0.f) ? acc.w : __expf(acc.w) - 1.f;
  }
  ((float4*)(out + (size_t)node * HD))[lane] = acc;
}

// ============================ launch ============================
extern "C" void kernel_launch(void* const* d_in, const int* in_sizes, int n_in,
                              void* d_out, int out_size, void* d_ws, size_t ws_size,
                              hipStream_t stream) {
  const int* nids = (const int*)d_in[0];
  const int* esrc = (const int*)d_in[1];
  const int* edst = (const int*)d_in[2];
  const float* emb = (const float*)d_in[3];
  const float* W1 = (const float*)d_in[4];
  const float* al1 = (const float*)d_in[5];
  const float* ar1 = (const float*)d_in[6];
  const float* b1 = (const float*)d_in[7];
  const float* W2 = (const float*)d_in[8];
  const float* al2 = (const float*)d_in[9];
  const float* ar2 = (const float*)d_in[10];
  const float* b2 = (const float*)d_in[11];
  float* out = (float*)d_out;

  char* w = (char*)d_ws;
  size_t off = 0;
  __bf16* fbuf = (__bf16*)(w + off); off += (size_t)NN * HD * 2;
  float* el = (float*)(w + off); off += (size_t)NN * NH * 4;
  float* er = (float*)(w + off); off += (size_t)NN * NH * 4;
  int* row_ptr = (int*)(w + off); off += (size_t)(NN + 1) * 4;
  int* counts = (int*)(w + off); off += (size_t)NN * 4;
  int* rank = (int*)(w + off); off += (size_t)EE * 4;
  int* csr_src = (int*)(w + off); off += (size_t)EE * 4;
  int* bsums = (int*)(w + off); off += 1024;
  __bf16* W1tH = (__bf16*)(w + off); off += (size_t)HD * HD * 2;
  __bf16* W1tL = (__bf16*)(w + off); off += (size_t)HD * HD * 2;
  __bf16* W2tH = (__bf16*)(w + off); off += (size_t)HD * HD * 2;
  __bf16* W2tL = (__bf16*)(w + off); off += (size_t)HD * HD * 2;

  int nbN = (NN + 255) / 256;
  int nbE = (EE + 255) / 256;

  k_zero_i32<<<nbN, 256, 0, stream>>>(counts, NN);
  k_count<<<nbE, 256, 0, stream>>>(edst, counts, rank);
  k_scan1<<<nbN, 256, 0, stream>>>(counts, row_ptr, bsums);
  k_scan2<<<1, 256, 0, stream>>>(bsums, nbN);
  k_scan3<<<nbN, 256, 0, stream>>>(row_ptr, bsums);
  k_scatter<<<nbE, 256, 0, stream>>>(esrc, edst, row_ptr, rank, csr_src);
  k_prep_w2<<<512, 256, 0, stream>>>(W1, W2, W1tH, W1tL, W2tH, W2tL);

  int gemm_grid = (NN + 63) / 64;
  int nbNode4 = (NN + 3) / 4;

  // ---- layer 1 ----
  k_gemm_mfma<<<gemm_grid, 256, 0, stream>>>(emb, nids, W1tH, W1tL, al1, ar1,
                                             fbuf, el, er, NN);
  k_aggregate<<<nbNode4, 256, 0, stream>>>(fbuf, el, er, row_ptr, csr_src, b1, out, 1);

  // ---- layer 2 ----
  k_gemm_mfma<<<gemm_grid, 256, 0, stream>>>(out, nullptr, W2tH, W2tL, al2, ar2,
                                             fbuf, el, er, NN);
  k_aggregate<<<nbNode4, 256, 0, stream>>>(fbuf, el, er, row_ptr, csr_src, b2, out, 0);
}